// Round 1
// 630.805 us; speedup vs baseline: 1.1735x; 1.1735x over previous
//
#include <hip/hip_runtime.h>

// TemporalPropagator on MI355X — bf16-MFMA, round 6.
// New this round:
//  * pow+T chain steps fused into one z=4 launch at 128x64 tiles (GEMM1's
//    proven 808-TF config, 512 blocks = 2/CU) — pows computed full-grid,
//    3 of 4 mirror launches deleted.
//  * build_A / mirror rewritten as 32x32 LDS-tiled transpose kernels
//    (coalesced both directions, padded stride -> conflict-free).
//  * conv2 vectorized (float4 in, short4 out).

using s8v = __attribute__((ext_vector_type(8))) short;
using s4v = __attribute__((ext_vector_type(4))) short;
using f4v = __attribute__((ext_vector_type(4))) float;

constexpr int Dn = 1024, TBn = 4096, Bn = 16;
constexpr size_t DD  = (size_t)Dn * Dn;
constexpr size_t TBD = (size_t)TBn * Dn;
constexpr int OUT1 = 2 * TBn * Dn;

#define MFMA(a, b, c) __builtin_amdgcn_mfma_f32_16x16x32_bf16(a, b, c, 0, 0, 0)

__device__ __forceinline__ short f2bf(float v) {
  unsigned u = __float_as_uint(v);
  return (short)((u + 0x7fffu + ((u >> 16) & 1u)) >> 16);
}
__device__ __forceinline__ float bf2f(short s) {
  return __uint_as_float(((unsigned)(unsigned short)s) << 16);
}

// ---------------- elementwise producers ----------------

// A = 0.5(R - R^T) + i*0.5(Im + Im^T), tiled: block handles tile pair (bi,bj),(bj,bi)
__global__ void build_A2t_k(const float* __restrict__ rre, const float* __restrict__ rim,
                            short* __restrict__ o0, short* __restrict__ o1) {
  __shared__ float tr[2][32][33];
  __shared__ float ti[2][32][33];
  int t = blockIdx.x, r = 0;
  while (t >= 32 - r) { t -= 32 - r; r++; }
  const int bi = r, bj = r + t;            // bj >= bi
  const int lx = threadIdx.x & 31, ly = threadIdx.x >> 5;
  for (int rr = ly; rr < 32; rr += 8) {
    tr[0][rr][lx] = rre[(size_t)(bi * 32 + rr) * Dn + bj * 32 + lx];
    ti[0][rr][lx] = rim[(size_t)(bi * 32 + rr) * Dn + bj * 32 + lx];
    tr[1][rr][lx] = rre[(size_t)(bj * 32 + rr) * Dn + bi * 32 + lx];
    ti[1][rr][lx] = rim[(size_t)(bj * 32 + rr) * Dn + bi * 32 + lx];
  }
  __syncthreads();
  for (int rr = ly; rr < 32; rr += 8) {
    size_t d0 = (size_t)(bi * 32 + rr) * Dn + bj * 32 + lx;
    o0[d0] = f2bf(0.5f * (tr[0][rr][lx] - tr[1][lx][rr]));
    o1[d0] = f2bf(0.5f * (ti[0][rr][lx] + ti[1][lx][rr]));
    if (bi != bj) {
      size_t d1 = (size_t)(bj * 32 + rr) * Dn + bi * 32 + lx;
      o0[d1] = f2bf(0.5f * (tr[1][rr][lx] - tr[0][lx][rr]));
      o1[d1] = f2bf(0.5f * (ti[1][rr][lx] + ti[0][lx][rr]));
    }
  }
}

__global__ void t02_k(const short* __restrict__ a0, const short* __restrict__ a1,
                      const short* __restrict__ p0, const short* __restrict__ p1,
                      short* __restrict__ o0, short* __restrict__ o1) {
  int idx = blockIdx.x * 256 + threadIdx.x;
  int i = idx >> 10, j = idx & 1023;
  o0[idx] = f2bf((i == j ? 1.f : 0.f) + 2.f * bf2f(a0[idx]) + bf2f(p0[idx]));
  o1[idx] = f2bf(2.f * bf2f(a1[idx]) + bf2f(p1[idx]));
}

// Hermitian conj-mirror of 4 planes (re0,im0,re1,im1), LDS-tiled.
__global__ void mirror_t_k(short* __restrict__ p0, short* __restrict__ p1,
                           short* __restrict__ p2, short* __restrict__ p3) {
  __shared__ short ts[4][32][34];
  int t = blockIdx.x, r = 0;
  while (t >= 32 - r) { t -= 32 - r; r++; }
  const int bi = r, bj = r + t;            // bj >= bi; read upper (bi,bj), write lower (bj,bi)
  const int lx = threadIdx.x & 31, ly = threadIdx.x >> 5;
  short* ps[4] = {p0, p1, p2, p3};
  #pragma unroll
  for (int pz = 0; pz < 4; pz++)
    for (int rr = ly; rr < 32; rr += 8)
      ts[pz][rr][lx] = ps[pz][(size_t)(bi * 32 + rr) * Dn + bj * 32 + lx];
  __syncthreads();
  #pragma unroll
  for (int pz = 0; pz < 4; pz++) {
    const short xs = (pz & 1) ? (short)0x8000 : (short)0;
    for (int rr = ly; rr < 32; rr += 8) {
      if (bj > bi || rr > lx)
        ps[pz][(size_t)(bj * 32 + rr) * Dn + bi * 32 + lx] = (short)(ts[pz][lx][rr] ^ xs);
    }
  }
}

__global__ void colscale2_k(const short* __restrict__ u0, const short* __restrict__ u1,
                            const float* __restrict__ ls, float sgn,
                            short* __restrict__ o0, short* __restrict__ o1) {
  int idx = blockIdx.x * 256 + threadIdx.x;
  int j = idx & 1023;
  float sv = expf(sgn * ls[j]);
  o0[idx] = f2bf(bf2f(u0[idx]) * sv);
  o1[idx] = f2bf(bf2f(u1[idx]) * sv);
}

// W1[n][k] = Minv[n][k]*op_decay[n]; W1[n][1024+k] = Minv[n][k]*op_forcing[n]
__global__ void w1build_k(const short* __restrict__ m0, const short* __restrict__ m1,
                          const float* __restrict__ odr, const float* __restrict__ odi,
                          const float* __restrict__ ofr, const float* __restrict__ ofi,
                          short* __restrict__ w0, short* __restrict__ w1) {
  int idx = blockIdx.x * 256 + threadIdx.x;
  int n = idx >> 10, k = idx & 1023;
  float vr = bf2f(m0[idx]), vi = bf2f(m1[idx]);
  size_t d0 = (size_t)n * 2048 + k, d1 = d0 + 1024;
  float dr = odr[n], di = odi[n], fr = ofr[n], fi = ofi[n];
  w0[d0] = f2bf(vr * dr - vi * di);
  w1[d0] = f2bf(vr * di + vi * dr);
  w0[d1] = f2bf(vr * fr - vi * fi);
  w1[d1] = f2bf(vr * fi + vi * fr);
}

__global__ void conv2_k(const float* __restrict__ re, const float* __restrict__ im,
                        short* __restrict__ orh, short* __restrict__ oih) {
  int idx = blockIdx.x * 256 + threadIdx.x;
  float4 a = ((const float4*)re)[idx];
  float4 b = ((const float4*)im)[idx];
  s4v va = {f2bf(a.x), f2bf(a.y), f2bf(a.z), f2bf(a.w)};
  s4v vb = {f2bf(b.x), f2bf(b.y), f2bf(b.z), f2bf(b.w)};
  ((s4v*)orh)[idx] = va;
  ((s4v*)oih)[idx] = vb;
}

// ---------------- fp32 small path ----------------

__global__ void ops_k(const float* __restrict__ ld, const float* __restrict__ lf,
                      const float* __restrict__ lawre, const float* __restrict__ lawim,
                      const float* __restrict__ dtp,
                      float* __restrict__ odr, float* __restrict__ odi,
                      float* __restrict__ ofr, float* __restrict__ ofi) {
  int d = blockIdx.x * 256 + threadIdx.x;
  float dt = dtp[0];
  float lre = -expf(ld[d]) + lawre[d];
  float lim = lf[d] + lawim[d];
  float Lre = -log1pf(expf(-lre));
  float zr = Lre * dt, zi = lim * dt;
  float er = expf(zr);
  float Odr = er * cosf(zi), Odi = er * sinf(zi);
  float m2 = zr * zr + zi * zi;
  float p1r, p1i;
  if (sqrtf(m2) < 1e-4f) {
    p1r = 1.f + 0.5f * zr + (zr * zr - zi * zi) * (1.f / 6.f);
    p1i = 0.5f * zi + (2.f * zr * zi) * (1.f / 6.f);
  } else {
    float nr = Odr - 1.f, ni = Odi, inv = 1.f / m2;
    p1r = (nr * zr + ni * zi) * inv;
    p1i = (ni * zr - nr * zi) * inv;
  }
  odr[d] = Odr; odi[d] = Odi;
  ofr[d] = p1r * dt; ofi[d] = p1i * dt;
}

template <bool SPLIT>
__global__ void mlpw_k(const float* __restrict__ in0, const float* __restrict__ in1,
                       const float* __restrict__ W, const float* __restrict__ bias,
                       float* __restrict__ out0, float* __restrict__ out1) {
  int wid = blockIdx.x * 4 + (threadIdx.x >> 6);
  int lane = threadIdx.x & 63;
  int b = wid >> 11, o = wid & 2047;
  const float* w0 = W + (size_t)o * 2048;
  float acc = 0.f;
  for (int c = lane; c < Dn; c += 64)
    acc += in0[b * Dn + c] * w0[c] + in1[b * Dn + c] * w0[Dn + c];
  for (int s = 32; s; s >>= 1) acc += __shfl_xor(acc, s);
  if (lane == 0) {
    acc += bias[o];
    if (SPLIT) {
      if (o < Dn) out0[b * Dn + o] = acc;
      else        out1[b * Dn + (o - Dn)] = acc;
    } else out0[b * 2048 + o] = acc;
  }
}

__global__ void flux_k(const float* __restrict__ fre, const float* __restrict__ fim,
                       const float* __restrict__ dre, const float* __restrict__ dim_,
                       const float* __restrict__ xm,
                       float* __restrict__ fnre, float* __restrict__ fnim,
                       float* __restrict__ outf) {
  int t = blockIdx.x * 256 + threadIdx.x;
  int b = t >> 10, d = t & 1023;
  float dr = 1.f / (1.f + expf(-dre[d]));
  float di = dim_[d];
  float fr = fre[t], fi = fim[t];
  float xr = xm[b * 2048 + d], xi = xm[b * 2048 + Dn + d];
  float nr = fr * dr - fi * di + xr;
  float ni = fr * di + fi * dr + xi;
  fnre[t] = nr; fnim[t] = ni;
  outf[OUT1 + t] = nr;
  outf[OUT1 + Bn * Dn + t] = ni;
}

__global__ void srcf_k(const float* __restrict__ sre, const float* __restrict__ sim,
                       const float* __restrict__ ofr, const float* __restrict__ ofi,
                       float* __restrict__ tre, float* __restrict__ tim) {
  int t = blockIdx.x * 256 + threadIdx.x;
  int d = t & 1023;
  float sr = sre[t], si = sim[t], fr = ofr[d], fi = ofi[d];
  tre[t] = sr * fr - si * fi;
  tim[t] = sr * fi + si * fr;
}

// ---------------- MFMA complex GEMM ----------------
// C[M][N] = sum_k X[m][k]*Y[k][n]; Y read from SY stored [N][K] (SY = Y^T).
// X, Y single bf16 planes (re, im). YNEG: 0 none, 1 conj, 2 -conj.
// TRI: triangular grid (upper tiles only, square, BM==BN).
// ADDX: 0 none, 1 always (O = X + X.Y), 2 runtime per-z via addxMask.
struct MGP {
  const short* X[4][2];
  const short* Y[4][2];
  short* O[4][2];
  const short* X2p[2];
  float* OF[2];
  const float* S[2];
  int M, K, N, Kx, addxMask;
};

template <int MI, int NI, int KS, int TRI, int X2, int ADDX, int SRC, int OUT, int YNEG>
__launch_bounds__(256, 2)
__global__ void mgemm_k(MGP g) {
  constexpr int BM = MI * 32, BN = NI * 32;
  __shared__ __align__(16) short As[2][KS * BM * 32];
  __shared__ __align__(16) short Bs[2][KS * BN * 32];
  const int tid = threadIdx.x;
  const int lane = tid & 63, wave = tid >> 6;
  const int wm = wave >> 1, wn = wave & 1;
  const int bz = blockIdx.z;
  const int fl = lane & 15, fq = lane >> 4;
  const int K = g.K, N = g.N, Kx = g.Kx;
  const int srow = lane >> 2;
  const int schunk = (lane & 3) * 8;

  int row0, col0;
  if constexpr (TRI) {
    int t = blockIdx.x, r = 0;
    const int gt = N / BN;
    while (t >= gt - r) { t -= gt - r; r++; }
    row0 = r * BM; col0 = (r + t) * BN;
  } else {
    row0 = blockIdx.y * BM; col0 = blockIdx.x * BN;
  }

  s8v sgn;
  #pragma unroll
  for (int i = 0; i < 8; i++) sgn[i] = (short)0x8000;

  f4v aR[MI][NI], aI[MI][NI];
  #pragma unroll
  for (int m = 0; m < MI; m++)
    #pragma unroll
    for (int n = 0; n < NI; n++)
      #pragma unroll
      for (int r = 0; r < 4; r++) { aR[m][n][r] = 0.f; aI[m][n][r] = 0.f; }

  for (int k0 = 0; k0 < K; k0 += 32 * KS) {
    // ---- stage X/Y planes (global -> LDS, 16B/lane, wave-uniform base) ----
    #pragma unroll
    for (int c = 0; c < KS; c++) {
      int kc = k0 + c * 32;
      const short* const* xs = g.X[bz];
      int kk = kc;
      if constexpr (X2) { if (kc >= Kx) { xs = g.X2p; kk = kc - Kx; } }
      #pragma unroll
      for (int p = 0; p < 2; p++)
        #pragma unroll
        for (int u = 0; u < BM / 64; u++) {
          int r = wave * (BM / 4) + u * 16 + srow;
          const short* gp = xs[p] + (size_t)(row0 + r) * Kx + kk + schunk;
          short* lp = &As[p][c * BM * 32 + (wave * (BM / 4) + u * 16) * 32];
          __builtin_amdgcn_global_load_lds((const __attribute__((address_space(1))) void*)gp,
                                           (__attribute__((address_space(3))) void*)lp, 16, 0, 0);
        }
      #pragma unroll
      for (int p = 0; p < 2; p++)
        #pragma unroll
        for (int u = 0; u < BN / 64; u++) {
          int r = wave * (BN / 4) + u * 16 + srow;
          const short* gp = g.Y[bz][p] + (size_t)(col0 + r) * K + kc + schunk;
          short* lp = &Bs[p][c * BN * 32 + (wave * (BN / 4) + u * 16) * 32];
          __builtin_amdgcn_global_load_lds((const __attribute__((address_space(1))) void*)gp,
                                           (__attribute__((address_space(3))) void*)lp, 16, 0, 0);
        }
    }
    __syncthreads();

    #pragma unroll
    for (int c = 0; c < KS; c++) {
      // B fragments (B[k][n]: n = lane&15, k = (lane>>4)*8 + j)
      s8v bf[NI][2];
      #pragma unroll
      for (int n = 0; n < NI; n++)
        #pragma unroll
        for (int p = 0; p < 2; p++)
          bf[n][p] = *(const s8v*)&Bs[p][c * BN * 32 + (wn * NI * 16 + n * 16 + fl) * 32 + fq * 8];
      if constexpr (YNEG == 1) {
        #pragma unroll
        for (int n = 0; n < NI; n++) bf[n][1] ^= sgn;
      } else if constexpr (YNEG == 2) {
        #pragma unroll
        for (int n = 0; n < NI; n++) bf[n][0] ^= sgn;
      }
      #pragma unroll
      for (int m = 0; m < MI; m++) {
        int arow = c * BM * 32 + (wm * MI * 16 + m * 16 + fl) * 32 + fq * 8;
        s8v arh = *(const s8v*)&As[0][arow];
        s8v aih = *(const s8v*)&As[1][arow];
        s8v nih = aih ^ sgn;
        #pragma unroll
        for (int n = 0; n < NI; n++) {
          f4v cr = aR[m][n], ci = aI[m][n];
          cr = MFMA(arh, bf[n][0], cr); cr = MFMA(nih, bf[n][1], cr);
          ci = MFMA(arh, bf[n][1], ci); ci = MFMA(aih, bf[n][0], ci);
          aR[m][n] = cr; aI[m][n] = ci;
        }
      }
    }
    __syncthreads();
  }

  // ---- epilogue: C/D layout col = lane&15, row = (lane>>4)*4 + reg ----
  #pragma unroll
  for (int m = 0; m < MI; m++) {
    #pragma unroll
    for (int n = 0; n < NI; n++) {
      int grb = row0 + wm * MI * 16 + m * 16 + fq * 4;
      int gc  = col0 + wn * NI * 16 + n * 16 + fl;
      #pragma unroll
      for (int r = 0; r < 4; r++) {
        int gr = grb + r;
        size_t gi = (size_t)gr * N + gc;
        float vr = aR[m][n][r], vi = aI[m][n][r];
        if (ADDX == 1 || (ADDX == 2 && ((g.addxMask >> bz) & 1))) {
          vr += bf2f(g.X[bz][0][gi]);
          vi += bf2f(g.X[bz][1][gi]);
        }
        if constexpr (SRC) {
          int sb = gr >> 8;
          vr += g.S[0][sb * Dn + gc];
          vi += g.S[1][sb * Dn + gc];
        }
        if constexpr (OUT == 1) {
          g.O[bz][0][gi] = f2bf(vr);
          g.O[bz][1][gi] = f2bf(vi);
        } else {
          g.OF[0][gi] = vr;
          g.OF[1][gi] = vi;
        }
      }
    }
  }
}

// ---------------- host ----------------

extern "C" void kernel_launch(void* const* d_in, const int* in_sizes, int n_in,
                              void* d_out, int out_size, void* d_ws, size_t ws_size,
                              hipStream_t stream) {
  (void)in_sizes; (void)n_in; (void)out_size; (void)ws_size;
  const float* h_re  = (const float*)d_in[0];
  const float* h_im  = (const float*)d_in[1];
  const float* x_re  = (const float*)d_in[2];
  const float* x_im  = (const float*)d_in[3];
  const float* xg_re = (const float*)d_in[4];
  const float* xg_im = (const float*)d_in[5];
  const float* fl_re = (const float*)d_in[6];
  const float* fl_im = (const float*)d_in[7];
  const float* dtp   = (const float*)d_in[8];
  const float* u_rre = (const float*)d_in[9];
  const float* u_rim = (const float*)d_in[10];
  const float* v_rre = (const float*)d_in[11];
  const float* v_rim = (const float*)d_in[12];
  const float* lsig  = (const float*)d_in[13];
  const float* dcre  = (const float*)d_in[14];
  const float* dcim  = (const float*)d_in[15];
  const float* mixw  = (const float*)d_in[16];
  const float* mixb  = (const float*)d_in[17];
  const float* projw = (const float*)d_in[18];
  const float* projb = (const float*)d_in[19];
  const float* ld_   = (const float*)d_in[20];
  const float* lf_   = (const float*)d_in[21];
  const float* lawre = (const float*)d_in[22];
  const float* lawim = (const float*)d_in[23];
  float* outf = (float*)d_out;

  short* wsS = (short*)d_ws;
  auto pl = [&](int i) { return wsS + (size_t)i * DD; };
  // plane map (unit = 1024x1024 bf16 = 2MB):
  //  0-1 A_u / XscV    2-3 A_v / XscU
  //  4-5 P0_u / Minv   6-7 P0_v / M
  //  8-9 P1_u \ later W1 [1024][2048]: re 8-9, im 10-11
  // 10-11 P1_v /
  // 12-13 Tb0_u, 14-15 Tb0_v \ later hp: re 12-15, im 16-19
  // 16-17 Tb1_u, 18-19 Tb1_v /
  // 20-21 U, 22-23 V          later xp: re 20-23, im 24-27
  // 28-35 ht (re 28-31, im 32-35)
  float* fbase = (float*)(wsS + (size_t)36 * DD);
  float* xm   = fbase;
  float* fnre = xm + 32768;
  float* fnim = fnre + 16384;
  float* sre  = fnim + 16384;
  float* sim  = sre + 16384;
  float* sfre = sim + 16384;
  float* sfim = sfre + 16384;
  float* odr  = sfim + 16384;
  float* odi  = odr + Dn;
  float* ofr  = odi + Dn;
  float* ofi  = ofr + Dn;

  const dim3 blk(256);
  const dim3 gTRI(136, 1, 2);   // 16*17/2 upper 64x64 tiles, z = {U,V}
  const dim3 gFULL(16, 16, 2);

  auto set2  = [&](const short** f, int u) { f[0] = pl(u); f[1] = pl(u + 1); };
  auto set2o = [&](short** f, int u) { f[0] = pl(u); f[1] = pl(u + 1); };

  // ---- build A (tiled transpose) ----
  build_A2t_k<<<528, blk, 0, stream>>>(u_rre, u_rim, pl(0), pl(1));
  build_A2t_k<<<528, blk, 0, stream>>>(v_rre, v_rim, pl(2), pl(3));

  // A2 = A @ A = -(A A^H) (Hermitian, upper tiles; YNEG=2) -> P0
  {
    MGP G{};
    set2(G.X[0], 0); set2(G.X[1], 2);
    set2(G.Y[0], 0); set2(G.Y[1], 2);
    set2o(G.O[0], 4); set2o(G.O[1], 6);
    G.M = G.K = G.N = G.Kx = 1024;
    mgemm_k<2,2,2,1,0,0,0,1,2><<<gTRI, blk, 0, stream>>>(G);
  }
  mirror_t_k<<<528, blk, 0, stream>>>(pl(4), pl(5), pl(6), pl(7));
  // T0 = I + 2A + A2
  t02_k<<<4096, blk, 0, stream>>>(pl(0), pl(1), pl(4), pl(5), pl(12), pl(13));
  t02_k<<<4096, blk, 0, stream>>>(pl(2), pl(3), pl(6), pl(7), pl(14), pl(15));

  // fused chain step, z=4 @ 128x64 tiles (2 blocks/CU):
  //   z0: powU  P'_u = P_u P_u^H (full, Hermitian-by-construction)
  //   z1: powV  P'_v = P_v P_v^H
  //   z2: T_u'  = T_u + T_u P_u^H   (ADDX via mask)
  //   z3: T_v'  = T_v + T_v P_v^H
  auto fused_step = [&](int pu, int pv, int tu, int tv,
                        int opu, int opv, int otu, int otv) {
    MGP G{};
    set2(G.X[0], pu); set2(G.X[1], pv); set2(G.X[2], tu); set2(G.X[3], tv);
    set2(G.Y[0], pu); set2(G.Y[1], pv); set2(G.Y[2], pu); set2(G.Y[3], pv);
    set2o(G.O[0], opu); set2o(G.O[1], opv); set2o(G.O[2], otu); set2o(G.O[3], otv);
    G.M = G.K = G.N = G.Kx = 1024;
    G.addxMask = 0b1100;
    mgemm_k<4,2,2,0,0,2,0,1,1><<<dim3(16, 8, 4), blk, 0, stream>>>(G);
  };
  fused_step(4, 6, 12, 14, 8, 10, 16, 18);   // A4  = A2^2 ; T1 = T0(I+A2)
  fused_step(8, 10, 16, 18, 4, 6, 12, 14);   // A8  = A4^2 ; T2 = T1(I+A4)
  fused_step(4, 6, 12, 14, 8, 10, 16, 18);   // A16 = A8^2 ; T3 = T2(I+A8)
  // T4 = T3(I+A16) -> U(20-21) / V(22-23)
  {
    MGP G{};
    set2(G.X[0], 16); set2(G.X[1], 18);
    set2(G.Y[0], 8); set2(G.Y[1], 10);
    set2o(G.O[0], 20); set2o(G.O[1], 22);
    G.M = G.K = G.N = G.Kx = 1024;
    mgemm_k<2,2,2,0,0,1,0,1,1><<<gFULL, blk, 0, stream>>>(G);
  }

  // ---- fp32 small path ----
  ops_k<<<4, blk, 0, stream>>>(ld_, lf_, lawre, lawim, dtp, odr, odi, ofr, ofi);
  mlpw_k<false><<<8192, blk, 0, stream>>>(xg_re, xg_im, mixw, mixb, xm, nullptr);
  flux_k<<<64, blk, 0, stream>>>(fl_re, fl_im, dcre, dcim, xm, fnre, fnim, outf);
  mlpw_k<true><<<8192, blk, 0, stream>>>(fnre, fnim, projw, projb, sre, sim);
  srcf_k<<<64, blk, 0, stream>>>(sre, sim, ofr, ofi, sfre, sfim);

  // ---- Minv = (V s^-1) conj(U)^T -> 4-5 ; M = (U s) conj(V)^T -> 6-7 ----
  colscale2_k<<<4096, blk, 0, stream>>>(pl(22), pl(23), lsig, -1.f, pl(0), pl(1)); // XscV
  colscale2_k<<<4096, blk, 0, stream>>>(pl(20), pl(21), lsig, +1.f, pl(2), pl(3)); // XscU
  {
    MGP G{};
    set2(G.X[0], 0); set2(G.X[1], 2);
    set2(G.Y[0], 20); set2(G.Y[1], 22);   // conj via YNEG=1
    set2o(G.O[0], 4); set2o(G.O[1], 6);
    G.M = G.K = G.N = G.Kx = 1024;
    mgemm_k<2,2,2,0,0,0,0,1,1><<<gFULL, blk, 0, stream>>>(G);
  }
  // W1 [1024][2048] = [Minv*od | Minv*of], re at 8-9, im at 10-11
  w1build_k<<<4096, blk, 0, stream>>>(pl(4), pl(5), odr, odi, ofr, ofi, pl(8), pl(10));
  // h, x -> single-bf16 planes (after MinvM: xp overwrites U/V)
  conv2_k<<<4096, blk, 0, stream>>>(h_re, h_im, pl(12), pl(16));
  conv2_k<<<4096, blk, 0, stream>>>(x_re, x_im, pl(20), pl(24));

  // ---- big GEMM 1: ht = [h|x] @ [W1d;W1f] + srcf -> single-bf16 ht ----
  {
    MGP G{};
    G.X[0][0] = pl(12); G.X[0][1] = pl(16);
    G.X2p[0] = pl(20); G.X2p[1] = pl(24);
    G.Y[0][0] = pl(8); G.Y[0][1] = pl(10);
    G.O[0][0] = pl(28); G.O[0][1] = pl(32);
    G.S[0] = sfre; G.S[1] = sfim;
    G.M = 4096; G.K = 2048; G.N = 1024; G.Kx = 1024;
    mgemm_k<4,2,2,0,1,0,1,1,0><<<dim3(16, 32, 1), blk, 0, stream>>>(G);
  }
  // ---- big GEMM 2: out = ht @ M^T -> fp32 d_out ----
  {
    MGP G{};
    G.X[0][0] = pl(28); G.X[0][1] = pl(32);
    G.Y[0][0] = pl(6); G.Y[0][1] = pl(7);
    G.OF[0] = outf; G.OF[1] = outf + TBD;
    G.M = 4096; G.K = 1024; G.N = 1024; G.Kx = 1024;
    mgemm_k<4,2,2,0,0,0,0,2,0><<<dim3(16, 32, 1), blk, 0, stream>>>(G);
  }
}